// Round 2
// baseline (704.655 us; speedup 1.0000x reference)
//
#include <hip/hip_runtime.h>
#include <math.h>

namespace {

typedef short bf8_t __attribute__((ext_vector_type(8)));   // 8 bf16 payloads
typedef float f32x4 __attribute__((ext_vector_type(4)));
typedef unsigned short u16;

constexpr int kB = 2, kS = 4096, kD = 512, kH = 8, kBH = 16;
constexpr float kScale = 0.125f;  // 1/sqrt(64)

__device__ __forceinline__ u16 f2bf(float x) {
  const unsigned u = __float_as_uint(x);
  return (u16)((u + 0x7FFFu + ((u >> 16) & 1u)) >> 16);
}
__device__ __forceinline__ float bf2f(u16 h) {
  return __uint_as_float(((unsigned)h) << 16);
}

// ---------------------------------------------------------------------------
// Vector-fp32 GEMM: C = A[M,512] @ W[512,512] + bias.  64x64 tile, 256 thr.
// MODE 0: per-head bf16 hi/lo   oHi/oLo[((b*H+h)*S + s)*64 + dk]
// MODE 1: fp32 row-major        oF[m*512 + n]
// MODE 2: fp32 transposed heads oF[(bh*64 + dv)*S + s]
// ---------------------------------------------------------------------------
template <int MODE>
__global__ __launch_bounds__(256) void gemm_kernel(
    const float* __restrict__ A, const float* __restrict__ W,
    const float* __restrict__ bias, u16* __restrict__ oHi,
    u16* __restrict__ oLo, float* __restrict__ oF) {
  __shared__ float As[16][68];  // [k][m] transposed
  __shared__ float Ws[16][68];  // [k][n]
  const int t = threadIdx.x;
  const int m0 = blockIdx.y * 64;
  const int n0 = blockIdx.x * 64;
  const int ty = t >> 4, tx = t & 15;
  const int lam = t >> 2, lac = t & 3;
  const int lwk = t >> 4, lwn = t & 15;

  float acc[4][4] = {};

  for (int k0 = 0; k0 < kD; k0 += 16) {
    const float4 av = *(const float4*)&A[(size_t)(m0 + lam) * kD + k0 + lac * 4];
    const float4 wv = *(const float4*)&W[(size_t)(k0 + lwk) * kD + n0 + lwn * 4];
    __syncthreads();
    As[lac * 4 + 0][lam] = av.x;
    As[lac * 4 + 1][lam] = av.y;
    As[lac * 4 + 2][lam] = av.z;
    As[lac * 4 + 3][lam] = av.w;
    *(float4*)&Ws[lwk][lwn * 4] = wv;
    __syncthreads();
#pragma unroll
    for (int kk = 0; kk < 16; ++kk) {
      const float4 a4 = *(const float4*)&As[kk][ty * 4];
      const float4 b4 = *(const float4*)&Ws[kk][tx * 4];
      const float a[4] = {a4.x, a4.y, a4.z, a4.w};
      const float b[4] = {b4.x, b4.y, b4.z, b4.w};
#pragma unroll
      for (int i = 0; i < 4; ++i)
#pragma unroll
        for (int j = 0; j < 4; ++j) acc[i][j] = fmaf(a[i], b[j], acc[i][j]);
    }
  }

  float bb[4];
#pragma unroll
  for (int j = 0; j < 4; ++j) bb[j] = bias[n0 + tx * 4 + j];

  if (MODE == 0) {
    const int h = n0 >> 6;  // one head per 64-wide n-tile
#pragma unroll
    for (int i = 0; i < 4; ++i) {
      const int m = m0 + ty * 4 + i;
      const int bI = m >> 12, s = m & (kS - 1);
      const int bh = bI * kH + h;
      union { u16 u[4]; uint2 q; } ph, pl;
#pragma unroll
      for (int j = 0; j < 4; ++j) {
        const float x = acc[i][j] + bb[j];
        ph.u[j] = f2bf(x);
        pl.u[j] = f2bf(x - bf2f(ph.u[j]));
      }
      const size_t off = ((size_t)bh * kS + s) * 64 + tx * 4;
      *(uint2*)&oHi[off] = ph.q;
      *(uint2*)&oLo[off] = pl.q;
    }
  } else if (MODE == 2) {
    const int h = n0 >> 6;
    const int bI = m0 >> 12;            // tile never straddles batch (64 | 4096)
    const int s0 = (m0 & (kS - 1)) + ty * 4;
    const int bh = bI * kH + h;
#pragma unroll
    for (int j = 0; j < 4; ++j) {
      const int dv = tx * 4 + j;
      float4 ov;
      ov.x = acc[0][j] + bb[j];
      ov.y = acc[1][j] + bb[j];
      ov.z = acc[2][j] + bb[j];
      ov.w = acc[3][j] + bb[j];
      *(float4*)&oF[((size_t)(bh * 64 + dv)) * kS + s0] = ov;
    }
  } else {
#pragma unroll
    for (int i = 0; i < 4; ++i) {
      const int m = m0 + ty * 4 + i;
      float4 ov;
      ov.x = acc[i][0] + bb[0];
      ov.y = acc[i][1] + bb[1];
      ov.z = acc[i][2] + bb[2];
      ov.w = acc[i][3] + bb[3];
      *(float4*)&oF[(size_t)m * kD + n0 + tx * 4] = ov;
    }
  }
}

// ---------------------------------------------------------------------------
// Column stats via bf16x3 MFMA:  Rl[bh][k] = 1 / sum_q exp(s[q,k]*scale)
// Orientation S = Q·K^T: A=Q frag (row=lane%16), B=K frag (col=lane%16).
// C layout (m89): row=(l>>4)*4+r, col=l&15  -> lane owns column k0+nt*16+lr.
// 1024 blocks (XCD-chunked), 256 thr; wave w covers q rows {q0+w*16..+15}.
// ---------------------------------------------------------------------------
__global__ __launch_bounds__(256) void colstats_kernel(
    const u16* __restrict__ Qhi, const u16* __restrict__ Qlo,
    const u16* __restrict__ Khi, const u16* __restrict__ Klo,
    float* __restrict__ Rl) {
  const int nid = (int)blockIdx.x;
  const int swz = (nid & 7) * 128 + (nid >> 3);  // 8 XCDs x 128-chunk (bijective)
  const int bh = swz >> 6;
  const int k0 = (swz & 63) << 6;
  const int t = threadIdx.x;
  const int w = t >> 6, l = t & 63;
  const int lr = l & 15, lg = l >> 4;
  const size_t base = (size_t)bh * kS * 64;

  // K fragments for all 64 columns, resident in regs for the whole kernel.
  bf8_t kbh[4][2], kbl[4][2];
#pragma unroll
  for (int nt = 0; nt < 4; ++nt)
#pragma unroll
    for (int kh = 0; kh < 2; ++kh) {
      const size_t off = base + (size_t)(k0 + nt * 16 + lr) * 64 + kh * 32 + lg * 8;
      kbh[nt][kh] = *(const bf8_t*)&Khi[off];
      kbl[nt][kh] = *(const bf8_t*)&Klo[off];
    }

  float lsum[4] = {0.f, 0.f, 0.f, 0.f};

  for (int q0 = 0; q0 < kS; q0 += 64) {
    bf8_t qah[2], qal[2];
    const size_t qoff = base + (size_t)(q0 + w * 16 + lr) * 64;
#pragma unroll
    for (int kh = 0; kh < 2; ++kh) {
      qah[kh] = *(const bf8_t*)&Qhi[qoff + kh * 32 + lg * 8];
      qal[kh] = *(const bf8_t*)&Qlo[qoff + kh * 32 + lg * 8];
    }
#pragma unroll
    for (int nt = 0; nt < 4; ++nt) {
      f32x4 acc = {0.f, 0.f, 0.f, 0.f};
#pragma unroll
      for (int kh = 0; kh < 2; ++kh) {
        acc = __builtin_amdgcn_mfma_f32_16x16x32_bf16(qah[kh], kbh[nt][kh], acc, 0, 0, 0);
        acc = __builtin_amdgcn_mfma_f32_16x16x32_bf16(qah[kh], kbl[nt][kh], acc, 0, 0, 0);
        acc = __builtin_amdgcn_mfma_f32_16x16x32_bf16(qal[kh], kbh[nt][kh], acc, 0, 0, 0);
      }
#pragma unroll
      for (int r = 0; r < 4; ++r) lsum[nt] += __expf(acc[r] * kScale);
    }
  }

  // Sum the 4 lane-groups holding the same column (lanes l, l^16, l^32, l^48).
#pragma unroll
  for (int nt = 0; nt < 4; ++nt) {
    float s = lsum[nt];
    s += __shfl_xor(s, 16, 64);
    s += __shfl_xor(s, 32, 64);
    lsum[nt] = s;
  }
  __shared__ float red[4][64];
  if (l < 16) {
#pragma unroll
    for (int nt = 0; nt < 4; ++nt) red[w][nt * 16 + l] = lsum[nt];
  }
  __syncthreads();
  if (t < 64) {
    const float s = red[0][t] + red[1][t] + red[2][t] + red[3][t];
    Rl[(size_t)bh * kS + k0 + t] = 1.0f / s;
  }
}

// ---------------------------------------------------------------------------
// V' = V * Rl broadcast along s, split into bf16 hi/lo.  [bh][dv][s] layout.
// ---------------------------------------------------------------------------
__global__ __launch_bounds__(256) void scale_split_kernel(
    const float* __restrict__ Vf, const float* __restrict__ Rl,
    u16* __restrict__ Vsh, u16* __restrict__ Vsl) {
  const int idx = blockIdx.x * 256 + threadIdx.x;  // 1,048,576 total
  const int s4 = (idx & 1023) << 2;
  const int bhdv = idx >> 10;
  const int bh = bhdv >> 6;
  const float4 v = *(const float4*)&Vf[(size_t)bhdv * kS + s4];
  const float4 r = *(const float4*)&Rl[(size_t)bh * kS + s4];
  const float x[4] = {v.x * r.x, v.y * r.y, v.z * r.z, v.w * r.w};
  union { u16 u[4]; uint2 q; } hh, ll;
#pragma unroll
  for (int j = 0; j < 4; ++j) {
    hh.u[j] = f2bf(x[j]);
    ll.u[j] = f2bf(x[j] - bf2f(hh.u[j]));
  }
  *(uint2*)&Vsh[(size_t)bhdv * kS + s4] = hh.q;
  *(uint2*)&Vsl[(size_t)bhdv * kS + s4] = ll.q;
}

// ---------------------------------------------------------------------------
// Attention output via bf16x3 MFMA, S^T orientation.
// Block: 128 q-rows (4 waves x 32q), loops 64-wide k tiles.
//   S^T = K·Q^T  (A=K from LDS, B=Q from regs) -> lane holds P for q=lr.
//   P packed in-register into PV's B-frag; V' staged k-PERMUTED in LDS so
//   PV's A-frag is a contiguous ds_read_b128 with a k-order matching P's.
//   O^T = V'^T·P^T accumulates in regs; scatter-store at end.
// ---------------------------------------------------------------------------
__global__ __launch_bounds__(256) void attn_kernel(
    const u16* __restrict__ Qhi, const u16* __restrict__ Qlo,
    const u16* __restrict__ Khi, const u16* __restrict__ Klo,
    const u16* __restrict__ Vsh, const u16* __restrict__ Vsl,
    float* __restrict__ AttnOut) {
  __shared__ u16 KsH[64 * 72], KsL[64 * 72];  // [k][dk], +8 pad
  __shared__ u16 VpH[64 * 72], VpL[64 * 72];  // [dv][k-permuted], +8 pad

  const int nid = (int)blockIdx.x;
  const int swz = (nid & 7) * 64 + (nid >> 3);  // 8 XCDs x 64-chunk (bijective)
  const int bh = swz >> 5;
  const int q0 = (swz & 31) << 7;
  const int t = threadIdx.x;
  const int w = t >> 6, l = t & 63;
  const int lr = l & 15, lg = l >> 4;
  const size_t base = (size_t)bh * kS * 64;

  // staging geometry: thread covers rows {srow, srow+32}, 8-elem chunk sc
  const int srow = t >> 3;
  const int sc = t & 7;
  const int sc8 = sc * 8;
  const int sub = sc & 3, half = sub >> 1;
  const int posA = ((sc >> 2) << 5) + ((sub & 1) << 4) + (half << 2);  // k-perm

  // Q fragments (persistent): B[dk][q], col q = lr.
  bf8_t qh[2][2], ql[2][2];
#pragma unroll
  for (int nt = 0; nt < 2; ++nt) {
    const size_t qoff = base + (size_t)(q0 + w * 32 + nt * 16 + lr) * 64;
#pragma unroll
    for (int kh = 0; kh < 2; ++kh) {
      qh[nt][kh] = *(const bf8_t*)&Qhi[qoff + kh * 32 + lg * 8];
      ql[nt][kh] = *(const bf8_t*)&Qlo[qoff + kh * 32 + lg * 8];
    }
  }

  f32x4 acco[4][2];
  {
    const f32x4 z = {0.f, 0.f, 0.f, 0.f};
#pragma unroll
    for (int mt = 0; mt < 4; ++mt)
#pragma unroll
      for (int nt = 0; nt < 2; ++nt) acco[mt][nt] = z;
  }

  uint4 rkh[2], rkl[2], rvh[2], rvl[2];
#pragma unroll
  for (int ri = 0; ri < 2; ++ri) {  // prologue: tile 0
    const int row = srow + ri * 32;
    rkh[ri] = *(const uint4*)&Khi[base + (size_t)row * 64 + sc8];
    rkl[ri] = *(const uint4*)&Klo[base + (size_t)row * 64 + sc8];
    rvh[ri] = *(const uint4*)&Vsh[(size_t)(bh * 64 + row) * kS + sc8];
    rvl[ri] = *(const uint4*)&Vsl[(size_t)(bh * 64 + row) * kS + sc8];
  }

  for (int kt = 0; kt < kS / 64; ++kt) {
    __syncthreads();  // previous tile's LDS reads complete
#pragma unroll
    for (int ri = 0; ri < 2; ++ri) {
      const int row = srow + ri * 32;
      *(uint4*)&KsH[row * 72 + sc8] = rkh[ri];
      *(uint4*)&KsL[row * 72 + sc8] = rkl[ri];
      uint2 a, b;
      a.x = rvh[ri].x; a.y = rvh[ri].y; b.x = rvh[ri].z; b.y = rvh[ri].w;
      *(uint2*)&VpH[row * 72 + posA] = a;
      *(uint2*)&VpH[row * 72 + posA + 8] = b;
      a.x = rvl[ri].x; a.y = rvl[ri].y; b.x = rvl[ri].z; b.y = rvl[ri].w;
      *(uint2*)&VpL[row * 72 + posA] = a;
      *(uint2*)&VpL[row * 72 + posA + 8] = b;
    }
    __syncthreads();  // tile staged

    if (kt + 1 < kS / 64) {  // prefetch next tile: latency hides under MFMA
      const int k0n = (kt + 1) * 64;
#pragma unroll
      for (int ri = 0; ri < 2; ++ri) {
        const int row = srow + ri * 32;
        rkh[ri] = *(const uint4*)&Khi[base + (size_t)(k0n + row) * 64 + sc8];
        rkl[ri] = *(const uint4*)&Klo[base + (size_t)(k0n + row) * 64 + sc8];
        rvh[ri] = *(const uint4*)&Vsh[(size_t)(bh * 64 + row) * kS + k0n + sc8];
        rvl[ri] = *(const uint4*)&Vsl[(size_t)(bh * 64 + row) * kS + k0n + sc8];
      }
    }

    // ---- QK^T: S^T = K·Q^T ----
    f32x4 accs[4][2];
#pragma unroll
    for (int mt = 0; mt < 4; ++mt) {
      bf8_t kfh[2], kfl[2];
#pragma unroll
      for (int kh = 0; kh < 2; ++kh) {
        kfh[kh] = *(const bf8_t*)&KsH[(mt * 16 + lr) * 72 + kh * 32 + lg * 8];
        kfl[kh] = *(const bf8_t*)&KsL[(mt * 16 + lr) * 72 + kh * 32 + lg * 8];
      }
#pragma unroll
      for (int nt = 0; nt < 2; ++nt) {
        f32x4 a = {0.f, 0.f, 0.f, 0.f};
#pragma unroll
        for (int kh = 0; kh < 2; ++kh) {
          a = __builtin_amdgcn_mfma_f32_16x16x32_bf16(kfh[kh], qh[nt][kh], a, 0, 0, 0);
          a = __builtin_amdgcn_mfma_f32_16x16x32_bf16(kfh[kh], ql[nt][kh], a, 0, 0, 0);
          a = __builtin_amdgcn_mfma_f32_16x16x32_bf16(kfl[kh], qh[nt][kh], a, 0, 0, 0);
        }
        accs[mt][nt] = a;
      }
    }

    // ---- P = exp(s*scale); pack hi/lo into PV B-frags in-register.
    // Lane owns kcol = mt*16 + lg*4 + r; slot order matches Vp's k-perm.
    bf8_t ph[2][2], pl[2][2];
#pragma unroll
    for (int nt = 0; nt < 2; ++nt)
#pragma unroll
      for (int kh = 0; kh < 2; ++kh) {
        union { u16 u[8]; bf8_t v; } uh, ul;
#pragma unroll
        for (int r = 0; r < 4; ++r) {
          const float x0 = __expf(accs[2 * kh][nt][r] * kScale);
          const u16 h0 = f2bf(x0);
          uh.u[r] = h0;
          ul.u[r] = f2bf(x0 - bf2f(h0));
          const float x1 = __expf(accs[2 * kh + 1][nt][r] * kScale);
          const u16 h1 = f2bf(x1);
          uh.u[4 + r] = h1;
          ul.u[4 + r] = f2bf(x1 - bf2f(h1));
        }
        ph[nt][kh] = uh.v;
        pl[nt][kh] = ul.v;
      }

    // ---- PV: O^T = V'^T · P^T ----
#pragma unroll
    for (int mt = 0; mt < 4; ++mt) {
      bf8_t vfh[2], vfl[2];
#pragma unroll
      for (int kh = 0; kh < 2; ++kh) {
        vfh[kh] = *(const bf8_t*)&VpH[(mt * 16 + lr) * 72 + kh * 32 + lg * 8];
        vfl[kh] = *(const bf8_t*)&VpL[(mt * 16 + lr) * 72 + kh * 32 + lg * 8];
      }
#pragma unroll
      for (int nt = 0; nt < 2; ++nt) {
        f32x4 a = acco[mt][nt];
#pragma unroll
        for (int kh = 0; kh < 2; ++kh) {
          a = __builtin_amdgcn_mfma_f32_16x16x32_bf16(vfh[kh], ph[nt][kh], a, 0, 0, 0);
          a = __builtin_amdgcn_mfma_f32_16x16x32_bf16(vfh[kh], pl[nt][kh], a, 0, 0, 0);
          a = __builtin_amdgcn_mfma_f32_16x16x32_bf16(vfl[kh], ph[nt][kh], a, 0, 0, 0);
        }
        acco[mt][nt] = a;
      }
    }
  }

  // ---- store O: lane has (dv = mt*16+lg*4+r, q = q0+w*32+nt*16+lr)
  const int bI = bh >> 3, h = bh & 7;
#pragma unroll
  for (int mt = 0; mt < 4; ++mt)
#pragma unroll
    for (int nt = 0; nt < 2; ++nt) {
      const int q = q0 + w * 32 + nt * 16 + lr;
#pragma unroll
      for (int r = 0; r < 4; ++r) {
        const int dv = mt * 16 + lg * 4 + r;
        AttnOut[((size_t)(bI * kS + q)) * kD + h * 64 + dv] = acco[mt][nt][r];
      }
    }
}

}  // namespace

extern "C" void kernel_launch(void* const* d_in, const int* in_sizes, int n_in,
                              void* d_out, int out_size, void* d_ws,
                              size_t ws_size, hipStream_t stream) {
  (void)in_sizes; (void)n_in; (void)out_size; (void)ws_size;
  const float* q  = (const float*)d_in[0];
  const float* k  = (const float*)d_in[1];
  const float* v  = (const float*)d_in[2];
  const float* Wq = (const float*)d_in[3];
  const float* bq = (const float*)d_in[4];
  const float* Wk = (const float*)d_in[5];
  const float* bk = (const float*)d_in[6];
  const float* Wv = (const float*)d_in[7];
  const float* bv = (const float*)d_in[8];
  const float* Wo = (const float*)d_in[9];
  const float* bo = (const float*)d_in[10];
  float* out = (float*)d_out;

  // Workspace layout: 6 x bf16[16*4096*64] + fp32[16*64*4096] (Vf, reused as
  // AttnOut after the scale pass) + fp32 Rl[16*4096].  Total ~67.4 MB.
  const size_t hE = (size_t)kBH * kS * 64;  // 4,194,304
  u16* Qhi = (u16*)d_ws;
  u16* Qlo = Qhi + hE;
  u16* Khi = Qlo + hE;
  u16* Klo = Khi + hE;
  u16* Vsh = Klo + hE;
  u16* Vsl = Vsh + hE;
  float* Vf = (float*)(Vsl + hE);           // [bh][dv][s]
  float* Rl = Vf + hE;
  float* AttnOut = Vf;                      // alias: Vf dead after scale pass

  const dim3 gemmGrid(kD / 64, (kB * kS) / 64);  // (8, 128)

  gemm_kernel<0><<<gemmGrid, 256, 0, stream>>>(q, Wq, bq, Qhi, Qlo, nullptr);
  gemm_kernel<0><<<gemmGrid, 256, 0, stream>>>(k, Wk, bk, Khi, Klo, nullptr);
  gemm_kernel<2><<<gemmGrid, 256, 0, stream>>>(v, Wv, bv, nullptr, nullptr, Vf);
  colstats_kernel<<<1024, 256, 0, stream>>>(Qhi, Qlo, Khi, Klo, Rl);
  scale_split_kernel<<<4096, 256, 0, stream>>>(Vf, Rl, Vsh, Vsl);
  attn_kernel<<<512, 256, 0, stream>>>(Qhi, Qlo, Khi, Klo, Vsh, Vsl, AttnOut);
  gemm_kernel<1><<<gemmGrid, 256, 0, stream>>>(AttnOut, Wo, bo, nullptr, nullptr, out);
}